// Round 1
// baseline (9638.293 us; speedup 1.0000x reference)
//
#include <hip/hip_runtime.h>

// PatientNeuralODE on MI355X: persistent fused kernel.
// B=16384, DIN=32, DOUT=16, H=128, S=48, T=64, N_SUB=8.
// One wave (64 threads) per block, 16 samples per wave, 1024 blocks.
// f16 MFMA (16x16x32) for all matmuls, fp32 accumulate, fp32 RK state.

typedef _Float16 half8 __attribute__((ext_vector_type(8)));
typedef float    floatx4 __attribute__((ext_vector_type(4)));

#define MFMA16(a, b, c) __builtin_amdgcn_mfma_f32_16x16x32_f16((a), (b), (c), 0, 0, 0)

__device__ __constant__ float RKA[6][5] = {
    {0.f, 0.f, 0.f, 0.f, 0.f},
    {0.2f, 0.f, 0.f, 0.f, 0.f},
    {3.f/40.f, 9.f/40.f, 0.f, 0.f, 0.f},
    {44.f/45.f, -56.f/15.f, 32.f/9.f, 0.f, 0.f},
    {19372.f/6561.f, -25360.f/2187.f, 64448.f/6561.f, -212.f/729.f, 0.f},
    {9017.f/3168.f, -355.f/33.f, 46732.f/5247.f, 49.f/176.f, -5103.f/18656.f}
};

__device__ __forceinline__ float fast_exp2(float v) {
#if __has_builtin(__builtin_amdgcn_exp2f)
    return __builtin_amdgcn_exp2f(v);
#else
    return exp2f(v);
#endif
}
__device__ __forceinline__ float fast_rcp(float v) {
#if __has_builtin(__builtin_amdgcn_rcpf)
    return __builtin_amdgcn_rcpf(v);
#else
    return 1.0f / v;
#endif
}
__device__ __forceinline__ float tanh_fast(float v) {
    // tanh(x) = 1 - 2/(exp2(2x*log2e)+1); saturates correctly at +-inf
    float t = fast_exp2(v * 2.8853900817779268f);
    return 1.0f - 2.0f * fast_rcp(t + 1.0f);
}
__device__ __forceinline__ float sigmoid_fast(float v) {
    return fast_rcp(1.0f + fast_exp2(v * -1.4426950408889634f));
}

__global__ void __launch_bounds__(64, 1)
node_fused(const float* __restrict__ meas, const float* __restrict__ pt,
           const float* __restrict__ Wenc, const float* __restrict__ benc,
           const float* __restrict__ W1,   const float* __restrict__ b1,
           const float* __restrict__ W2,   const float* __restrict__ b2,
           const float* __restrict__ W3,   const float* __restrict__ b3,
           const float* __restrict__ Wout, const float* __restrict__ bout,
           float* __restrict__ outp, float* __restrict__ stat)
{
    const int lane = threadIdx.x;        // 0..63
    const int g    = lane >> 4;          // k-chunk group 0..3
    const int sl   = lane & 15;          // A-layout row (sample) / C-layout col
    const int sbase = blockIdx.x * 16;   // first sample of this wave

    __shared__ _Float16 hbuf[16 * 136];  // h transpose buffer [sample][128+pad]
    __shared__ float    sbuf[16 * 52];   // f32 transpose buffer [sample][48+pad]
    __shared__ half8    wlds[15 * 64];   // frag-packed W3(12), Wout(2), Wenc(1)

    // ---------------- weight fragments ----------------
    // B-frag layout: lane holds B[k][c], c = lane&15, k = 32*kt + 8*(lane>>4) + j
    half8 w1f[2][8], w2f[4][8];
#pragma unroll
    for (int kt = 0; kt < 2; ++kt)
#pragma unroll
        for (int nt = 0; nt < 8; ++nt) {
            half8 f;
#pragma unroll
            for (int j = 0; j < 8; ++j) {
                int k = 32*kt + 8*g + j;
                f[j] = (_Float16)(k < 48 ? W1[k*128 + 16*nt + sl] : 0.f);
            }
            w1f[kt][nt] = f;
        }
#pragma unroll
    for (int kt = 0; kt < 4; ++kt)
#pragma unroll
        for (int nt = 0; nt < 8; ++nt) {
            half8 f;
#pragma unroll
            for (int j = 0; j < 8; ++j) {
                int k = 32*kt + 8*g + j;
                f[j] = (_Float16)W2[k*128 + 16*nt + sl];
            }
            w2f[kt][nt] = f;
        }
#pragma unroll
    for (int kt = 0; kt < 4; ++kt)
#pragma unroll
        for (int nt = 0; nt < 3; ++nt) {
            half8 f;
#pragma unroll
            for (int j = 0; j < 8; ++j) {
                int k = 32*kt + 8*g + j;
                f[j] = (_Float16)W3[k*48 + 16*nt + sl];
            }
            wlds[(kt*3 + nt)*64 + lane] = f;
        }
#pragma unroll
    for (int kt = 0; kt < 2; ++kt) {
        half8 f;
#pragma unroll
        for (int j = 0; j < 8; ++j) {
            int k = 32*kt + 8*g + j;
            f[j] = (_Float16)(k < 48 ? Wout[k*16 + sl] : 0.f);
        }
        wlds[(12 + kt)*64 + lane] = f;
    }
    {
        half8 f;
#pragma unroll
        for (int j = 0; j < 8; ++j) {
            int k = 8*g + j;              // K=32 exactly
            f[j] = (_Float16)Wenc[k*16 + sl];
        }
        wlds[14*64 + lane] = f;
    }

    float b1p[8], b2p[8], b3p[3];
#pragma unroll
    for (int n = 0; n < 8; ++n) { b1p[n] = b1[16*n + sl]; b2p[n] = b2[16*n + sl]; }
#pragma unroll
    for (int n = 0; n < 3; ++n) b3p[n] = b3[16*n + sl];
    const float boutp = bout[sl];
    const float bencp = benc[sl];

    // ---------------- state init (encoder) ----------------
    // per-lane state x in A-frag layout: j<8 -> dim 8g+j ; j>=8 -> dim 32+8g+(j-8)
    // (valid only for g<2; lanes g>=2 keep x[8..15]==0 forever)
    float x[16];
    {
        const float* mrow = meas + (size_t)(sbase + sl) * 32 + 8*g;
        float4 m0 = *(const float4*)mrow;
        float4 m1 = *(const float4*)(mrow + 4);
        x[0]=m0.x; x[1]=m0.y; x[2]=m0.z; x[3]=m0.w;
        x[4]=m1.x; x[5]=m1.y; x[6]=m1.z; x[7]=m1.w;
        half8 a0;
#pragma unroll
        for (int j = 0; j < 8; ++j) a0[j] = (_Float16)x[j];
        floatx4 acc = {0.f, 0.f, 0.f, 0.f};
        acc = MFMA16(a0, wlds[14*64 + lane], acc);
        // C layout: row(sample)=4g+r, col(hidden)=sl
#pragma unroll
        for (int r = 0; r < 4; ++r) sbuf[(4*g + r)*52 + sl] = acc[r] + bencp;
        if (g < 2) {
            float4 v0 = *(const float4*)&sbuf[sl*52 + 8*g];
            float4 v1 = *(const float4*)&sbuf[sl*52 + 8*g + 4];
            x[8]=v0.x;  x[9]=v0.y;  x[10]=v0.z; x[11]=v0.w;
            x[12]=v1.x; x[13]=v1.y; x[14]=v1.z; x[15]=v1.w;
        } else {
#pragma unroll
            for (int j = 8; j < 16; ++j) x[j] = 0.f;
        }
    }

    // ---------------- RHS evaluation ----------------
    auto feval = [&](const float* xsv, float* ko) {
        half8 a0, a1;
#pragma unroll
        for (int j = 0; j < 8; ++j) { a0[j] = (_Float16)xsv[j]; a1[j] = (_Float16)xsv[8+j]; }
        // L1: [16,48]@[48,128]
#pragma unroll
        for (int n = 0; n < 8; ++n) {
            floatx4 acc = {0.f, 0.f, 0.f, 0.f};
            acc = MFMA16(a0, w1f[0][n], acc);
            acc = MFMA16(a1, w1f[1][n], acc);
#pragma unroll
            for (int r = 0; r < 4; ++r)
                hbuf[(4*g + r)*136 + 16*n + sl] = (_Float16)tanh_fast(acc[r] + b1p[n]);
        }
        half8 hf0 = *(const half8*)&hbuf[sl*136 +  0 + 8*g];
        half8 hf1 = *(const half8*)&hbuf[sl*136 + 32 + 8*g];
        half8 hf2 = *(const half8*)&hbuf[sl*136 + 64 + 8*g];
        half8 hf3 = *(const half8*)&hbuf[sl*136 + 96 + 8*g];
        // L2: [16,128]@[128,128]
#pragma unroll
        for (int n = 0; n < 8; ++n) {
            floatx4 acc = {0.f, 0.f, 0.f, 0.f};
            acc = MFMA16(hf0, w2f[0][n], acc);
            acc = MFMA16(hf1, w2f[1][n], acc);
            acc = MFMA16(hf2, w2f[2][n], acc);
            acc = MFMA16(hf3, w2f[3][n], acc);
#pragma unroll
            for (int r = 0; r < 4; ++r)
                hbuf[(4*g + r)*136 + 16*n + sl] = (_Float16)tanh_fast(acc[r] + b2p[n]);
        }
        half8 q0 = *(const half8*)&hbuf[sl*136 +  0 + 8*g];
        half8 q1 = *(const half8*)&hbuf[sl*136 + 32 + 8*g];
        half8 q2 = *(const half8*)&hbuf[sl*136 + 64 + 8*g];
        half8 q3 = *(const half8*)&hbuf[sl*136 + 96 + 8*g];
        // L3: [16,128]@[128,48] (f32 result = k)
#pragma unroll
        for (int nt = 0; nt < 3; ++nt) {
            floatx4 acc = {0.f, 0.f, 0.f, 0.f};
            acc = MFMA16(q0, wlds[(0*3 + nt)*64 + lane], acc);
            acc = MFMA16(q1, wlds[(1*3 + nt)*64 + lane], acc);
            acc = MFMA16(q2, wlds[(2*3 + nt)*64 + lane], acc);
            acc = MFMA16(q3, wlds[(3*3 + nt)*64 + lane], acc);
#pragma unroll
            for (int r = 0; r < 4; ++r)
                sbuf[(4*g + r)*52 + 16*nt + sl] = acc[r] + b3p[nt];
        }
        float4 v0 = *(const float4*)&sbuf[sl*52 + 8*g];
        float4 v1 = *(const float4*)&sbuf[sl*52 + 8*g + 4];
        ko[0]=v0.x; ko[1]=v0.y; ko[2]=v0.z; ko[3]=v0.w;
        ko[4]=v1.x; ko[5]=v1.y; ko[6]=v1.z; ko[7]=v1.w;
        if (g < 2) {
            float4 u0 = *(const float4*)&sbuf[sl*52 + 32 + 8*g];
            float4 u1 = *(const float4*)&sbuf[sl*52 + 32 + 8*g + 4];
            ko[8]=u0.x;  ko[9]=u0.y;  ko[10]=u0.z; ko[11]=u0.w;
            ko[12]=u1.x; ko[13]=u1.y; ko[14]=u1.z; ko[15]=u1.w;
        } else {
#pragma unroll
            for (int j = 8; j < 16; ++j) ko[j] = 0.f;
        }
    };

    // ---------------- output writers ----------------
    auto write_states = [&](int t) {
        *(float4*)&sbuf[sl*52 + 8*g    ] = make_float4(x[0], x[1], x[2], x[3]);
        *(float4*)&sbuf[sl*52 + 8*g + 4] = make_float4(x[4], x[5], x[6], x[7]);
        if (g < 2) {
            *(float4*)&sbuf[sl*52 + 32 + 8*g    ] = make_float4(x[8],  x[9],  x[10], x[11]);
            *(float4*)&sbuf[sl*52 + 32 + 8*g + 4] = make_float4(x[12], x[13], x[14], x[15]);
        }
#pragma unroll
        for (int q = 0; q < 3; ++q) {
            int idx = q*64 + lane;          // 0..191 = 16 samples * 12 chunks
            int sm  = idx / 12;
            int off = idx - sm*12;
            float4 v = *(const float4*)&sbuf[sm*52 + off*4];
            *(float4*)(stat + (size_t)(sbase + sm)*3072 + (size_t)t*48 + off*4) = v;
        }
    };
    auto write_outputs = [&](int t) {
        half8 a0, a1;
#pragma unroll
        for (int j = 0; j < 8; ++j) { a0[j] = (_Float16)x[j]; a1[j] = (_Float16)x[8+j]; }
        floatx4 acc = {0.f, 0.f, 0.f, 0.f};
        acc = MFMA16(a0, wlds[12*64 + lane], acc);
        acc = MFMA16(a1, wlds[13*64 + lane], acc);
#pragma unroll
        for (int r = 0; r < 4; ++r)
            sbuf[(4*g + r)*52 + sl] = sigmoid_fast(acc[r] + boutp);
        int sm = lane >> 2, qq = lane & 3;
        float4 v = *(const float4*)&sbuf[sm*52 + qq*4];
        *(float4*)(outp + (size_t)(sbase + sm)*1024 + (size_t)t*16 + qq*4) = v;
    };

    write_states(0);
    write_outputs(0);

    // ---------------- time integration ----------------
    float k1[16], k2[16], k3[16], k4[16], k5[16], k6[16], ktmp[16], xs[16];
#pragma unroll
    for (int j = 0; j < 16; ++j) { k1[j]=0.f; k2[j]=0.f; k3[j]=0.f; k4[j]=0.f; k5[j]=0.f; k6[j]=0.f; }

#pragma unroll 1
    for (int iv = 0; iv < 63; ++iv) {
        const float hh = (pt[iv+1] - pt[iv]) * 0.125f;   // dt / N_SUB
#pragma unroll 1
        for (int sub = 0; sub < 8; ++sub) {
#pragma unroll 1
            for (int st = 0; st < 6; ++st) {
                const float c0 = RKA[st][0], c1 = RKA[st][1], c2 = RKA[st][2],
                            c3 = RKA[st][3], c4 = RKA[st][4];
#pragma unroll
                for (int j = 0; j < 16; ++j)
                    xs[j] = x[j] + hh*(c0*k1[j] + c1*k2[j] + c2*k3[j] + c3*k4[j] + c4*k5[j]);
                feval(xs, ktmp);
                if (st == 0) {
#pragma unroll
                    for (int j = 0; j < 16; ++j) k1[j] = ktmp[j];
                } else if (st == 1) {
#pragma unroll
                    for (int j = 0; j < 16; ++j) k2[j] = ktmp[j];
                } else if (st == 2) {
#pragma unroll
                    for (int j = 0; j < 16; ++j) k3[j] = ktmp[j];
                } else if (st == 3) {
#pragma unroll
                    for (int j = 0; j < 16; ++j) k4[j] = ktmp[j];
                } else if (st == 4) {
#pragma unroll
                    for (int j = 0; j < 16; ++j) k5[j] = ktmp[j];
                } else {
#pragma unroll
                    for (int j = 0; j < 16; ++j) k6[j] = ktmp[j];
                }
            }
#pragma unroll
            for (int j = 0; j < 16; ++j)
                x[j] += hh*((35.f/384.f)*k1[j] + (500.f/1113.f)*k3[j] + (125.f/192.f)*k4[j]
                          + (-2187.f/6784.f)*k5[j] + (11.f/84.f)*k6[j]);
        }
        write_states(iv + 1);
        write_outputs(iv + 1);
    }
}

extern "C" void kernel_launch(void* const* d_in, const int* in_sizes, int n_in,
                              void* d_out, int out_size, void* d_ws, size_t ws_size,
                              hipStream_t stream) {
    const float* meas = (const float*)d_in[0];
    const float* pt   = (const float*)d_in[1];
    const float* Wenc = (const float*)d_in[2];
    const float* benc = (const float*)d_in[3];
    const float* W1   = (const float*)d_in[4];
    const float* b1   = (const float*)d_in[5];
    const float* W2   = (const float*)d_in[6];
    const float* b2   = (const float*)d_in[7];
    const float* W3   = (const float*)d_in[8];
    const float* b3   = (const float*)d_in[9];
    const float* Wout = (const float*)d_in[10];
    const float* bout = (const float*)d_in[11];
    float* outp = (float*)d_out;                        // [B, T, 16]
    float* stat = outp + (size_t)16384 * 64 * 16;       // [B, T, 48]
    hipLaunchKernelGGL(node_fused, dim3(1024), dim3(64), 0, stream,
                       meas, pt, Wenc, benc, W1, b1, W2, b2, W3, b3, Wout, bout,
                       outp, stat);
}

// Round 2
// 6808.389 us; speedup vs baseline: 1.4156x; 1.4156x over previous
//
#include <hip/hip_runtime.h>

// PatientNeuralODE on MI355X, round 2: 2 cooperating waves per block.
// B=16384, DIN=32, DOUT=16, H=128, S=48, T=64, N_SUB=8.
// 1024 blocks x 128 threads; 16 samples per block; waves split the hidden
// dim (4 of 8 N-tiles each) in L1/L2, redundant L3 + RK combine.
// f16 MFMA 16x16x32, fp32 accum, fp32 state. 3 barriers per RHS eval.

typedef _Float16 half8 __attribute__((ext_vector_type(8)));
typedef float    floatx4 __attribute__((ext_vector_type(4)));

#define MFMA16(a, b, c) __builtin_amdgcn_mfma_f32_16x16x32_f16((a), (b), (c), 0, 0, 0)

__device__ __forceinline__ float fast_exp2(float v) {
#if __has_builtin(__builtin_amdgcn_exp2f)
    return __builtin_amdgcn_exp2f(v);
#else
    return exp2f(v);
#endif
}
__device__ __forceinline__ float fast_rcp(float v) {
#if __has_builtin(__builtin_amdgcn_rcpf)
    return __builtin_amdgcn_rcpf(v);
#else
    return 1.0f / v;
#endif
}
__device__ __forceinline__ float tanh_fast(float v) {
    float t = fast_exp2(v * 2.8853900817779268f);
    return 1.0f - 2.0f * fast_rcp(t + 1.0f);
}
__device__ __forceinline__ float sigmoid_fast(float v) {
    return fast_rcp(1.0f + fast_exp2(v * -1.4426950408889634f));
}

#define HSTR 136   // hbuf row stride (halfs): 272B, 16B-aligned rows
#define SSTR 52    // k/state buffer row stride (floats)

__global__ void __launch_bounds__(128, 2)
node_fused(const float* __restrict__ meas, const float* __restrict__ pt,
           const float* __restrict__ Wenc, const float* __restrict__ benc,
           const float* __restrict__ W1,   const float* __restrict__ b1,
           const float* __restrict__ W2,   const float* __restrict__ b2,
           const float* __restrict__ W3,   const float* __restrict__ b3,
           const float* __restrict__ Wout, const float* __restrict__ bout,
           float* __restrict__ outp, float* __restrict__ stat)
{
    const int tid  = threadIdx.x;
    const int wid  = tid >> 6;           // wave id 0/1
    const int lane = tid & 63;
    const int g    = lane >> 4;          // k-chunk group 0..3
    const int sl   = lane & 15;          // sample (A row / C col)
    const int sbase = blockIdx.x * 16;

    __shared__ _Float16 hbufA[16 * HSTR];   // L1 output transpose buffer
    __shared__ _Float16 hbufB[16 * HSTR];   // L2 output transpose buffer
    __shared__ float    kbc[16 * SSTR];     // common k buffer (k1/k3/k4/k6, staging)
    __shared__ float    kb2[16 * SSTR];     // k2 (LDS-resident)
    __shared__ float    kb5[16 * SSTR];     // k5 (LDS-resident)
    __shared__ half8    wlds[15 * 64];      // W3(12) + Wout(2) + Wenc(1) frags

    // ---------------- weight fragments (per-wave N-split) ----------------
    // B-frag: lane holds B[k][c], c = 16*nn + sl, k = 32*kt + 8*g + j
    half8 w1f[2][4], w2f[4][4];
#pragma unroll
    for (int kt = 0; kt < 2; ++kt)
#pragma unroll
        for (int n = 0; n < 4; ++n) {
            const int col = 16 * (4*wid + n) + sl;
            half8 f;
#pragma unroll
            for (int j = 0; j < 8; ++j) {
                int k = 32*kt + 8*g + j;
                f[j] = (_Float16)(k < 48 ? W1[k*128 + col] : 0.f);
            }
            w1f[kt][n] = f;
        }
#pragma unroll
    for (int kt = 0; kt < 4; ++kt)
#pragma unroll
        for (int n = 0; n < 4; ++n) {
            const int col = 16 * (4*wid + n) + sl;
            half8 f;
#pragma unroll
            for (int j = 0; j < 8; ++j)
                f[j] = (_Float16)W2[(32*kt + 8*g + j)*128 + col];
            w2f[kt][n] = f;
        }
    // LDS weight fragments, staging split across the two waves
    for (int s = wid; s < 12; s += 2) {
        int kt = s / 3, nt = s - 3*kt;
        half8 f;
#pragma unroll
        for (int j = 0; j < 8; ++j)
            f[j] = (_Float16)W3[(32*kt + 8*g + j)*48 + 16*nt + sl];
        wlds[s*64 + lane] = f;
    }
    if (wid == 0) {
#pragma unroll
        for (int kt = 0; kt < 2; ++kt) {
            half8 f;
#pragma unroll
            for (int j = 0; j < 8; ++j) {
                int k = 32*kt + 8*g + j;
                f[j] = (_Float16)(k < 48 ? Wout[k*16 + sl] : 0.f);
            }
            wlds[(12 + kt)*64 + lane] = f;
        }
    } else {
        half8 f;
#pragma unroll
        for (int j = 0; j < 8; ++j)
            f[j] = (_Float16)Wenc[(8*g + j)*16 + sl];
        wlds[14*64 + lane] = f;
    }

    float b1p[4], b2p[4], b3p[3];
#pragma unroll
    for (int n = 0; n < 4; ++n) {
        b1p[n] = b1[16*(4*wid + n) + sl];
        b2p[n] = b2[16*(4*wid + n) + sl];
    }
#pragma unroll
    for (int n = 0; n < 3; ++n) b3p[n] = b3[16*n + sl];
    const float boutp = bout[sl];
    const float bencp = benc[sl];

    __syncthreads();   // wlds ready

    // ---------------- helpers ----------------
    auto ldsk = [&](const float* kb, float* kv) {
        float4 v0 = *(const float4*)&kb[sl*SSTR + 8*g];
        float4 v1 = *(const float4*)&kb[sl*SSTR + 8*g + 4];
        kv[0]=v0.x; kv[1]=v0.y; kv[2]=v0.z; kv[3]=v0.w;
        kv[4]=v1.x; kv[5]=v1.y; kv[6]=v1.z; kv[7]=v1.w;
        if (g < 2) {
            float4 u0 = *(const float4*)&kb[sl*SSTR + 32 + 8*g];
            float4 u1 = *(const float4*)&kb[sl*SSTR + 32 + 8*g + 4];
            kv[8]=u0.x;  kv[9]=u0.y;  kv[10]=u0.z; kv[11]=u0.w;
            kv[12]=u1.x; kv[13]=u1.y; kv[14]=u1.z; kv[15]=u1.w;
        } else {
#pragma unroll
            for (int j = 8; j < 16; ++j) kv[j] = 0.f;
        }
    };
    auto mkfrags = [&](const float* v, half8& A0, half8& A1) {
#pragma unroll
        for (int j = 0; j < 8; ++j) { A0[j] = (_Float16)v[j]; A1[j] = (_Float16)v[8+j]; }
    };

    // feval: writes k' = hs * f(xs) into kb (C layout). 3 barriers.
    auto feval = [&](half8 A0, half8 A1, float* kb, float hs) {
        // L1: this wave's 4 N-tiles
#pragma unroll
        for (int n = 0; n < 4; ++n) {
            floatx4 acc = {b1p[n], b1p[n], b1p[n], b1p[n]};
            acc = MFMA16(A0, w1f[0][n], acc);
            acc = MFMA16(A1, w1f[1][n], acc);
            const int col = 16*(4*wid + n) + sl;
#pragma unroll
            for (int r = 0; r < 4; ++r)
                hbufA[(4*g + r)*HSTR + col] = (_Float16)tanh_fast(acc[r]);
        }
        __syncthreads();
        half8 h0 = *(const half8*)&hbufA[sl*HSTR +  0 + 8*g];
        half8 h1 = *(const half8*)&hbufA[sl*HSTR + 32 + 8*g];
        half8 h2 = *(const half8*)&hbufA[sl*HSTR + 64 + 8*g];
        half8 h3 = *(const half8*)&hbufA[sl*HSTR + 96 + 8*g];
        // L2
#pragma unroll
        for (int n = 0; n < 4; ++n) {
            floatx4 acc = {b2p[n], b2p[n], b2p[n], b2p[n]};
            acc = MFMA16(h0, w2f[0][n], acc);
            acc = MFMA16(h1, w2f[1][n], acc);
            acc = MFMA16(h2, w2f[2][n], acc);
            acc = MFMA16(h3, w2f[3][n], acc);
            const int col = 16*(4*wid + n) + sl;
#pragma unroll
            for (int r = 0; r < 4; ++r)
                hbufB[(4*g + r)*HSTR + col] = (_Float16)tanh_fast(acc[r]);
        }
        __syncthreads();
        half8 q0 = *(const half8*)&hbufB[sl*HSTR +  0 + 8*g];
        half8 q1 = *(const half8*)&hbufB[sl*HSTR + 32 + 8*g];
        half8 q2 = *(const half8*)&hbufB[sl*HSTR + 64 + 8*g];
        half8 q3 = *(const half8*)&hbufB[sl*HSTR + 96 + 8*g];
        // L3 (redundant in both waves; writes split: wave0 nt 0,1 / wave1 nt 2)
#pragma unroll
        for (int nt = 0; nt < 3; ++nt) {
            floatx4 acc = {b3p[nt], b3p[nt], b3p[nt], b3p[nt]};
            acc = MFMA16(q0, wlds[(0*3 + nt)*64 + lane], acc);
            acc = MFMA16(q1, wlds[(1*3 + nt)*64 + lane], acc);
            acc = MFMA16(q2, wlds[(2*3 + nt)*64 + lane], acc);
            acc = MFMA16(q3, wlds[(3*3 + nt)*64 + lane], acc);
            if ((nt == 2) == (wid == 1)) {
#pragma unroll
                for (int r = 0; r < 4; ++r)
                    kb[(4*g + r)*SSTR + 16*nt + sl] = hs * acc[r];
            }
        }
        __syncthreads();
    };

    // ---------------- encoder ----------------
    float x[16];
    {
        const float* mrow = meas + (size_t)(sbase + sl)*32 + 8*g;
        float4 m0 = *(const float4*)mrow;
        float4 m1 = *(const float4*)(mrow + 4);
        x[0]=m0.x; x[1]=m0.y; x[2]=m0.z; x[3]=m0.w;
        x[4]=m1.x; x[5]=m1.y; x[6]=m1.z; x[7]=m1.w;
        half8 A0;
#pragma unroll
        for (int j = 0; j < 8; ++j) A0[j] = (_Float16)x[j];
        floatx4 acc = {bencp, bencp, bencp, bencp};
        acc = MFMA16(A0, wlds[14*64 + lane], acc);
#pragma unroll
        for (int r = 0; r < 4; ++r) kbc[(4*g + r)*SSTR + sl] = acc[r];
        if (g < 2) {
            float4 v0 = *(const float4*)&kbc[sl*SSTR + 8*g];
            float4 v1 = *(const float4*)&kbc[sl*SSTR + 8*g + 4];
            x[8]=v0.x;  x[9]=v0.y;  x[10]=v0.z; x[11]=v0.w;
            x[12]=v1.x; x[13]=v1.y; x[14]=v1.z; x[15]=v1.w;
        } else {
#pragma unroll
            for (int j = 8; j < 16; ++j) x[j] = 0.f;
        }
    }

    // ---------------- output writers ----------------
    auto write_states = [&](int ts) {
        *(float4*)&kbc[sl*SSTR + 8*g    ] = make_float4(x[0], x[1], x[2], x[3]);
        *(float4*)&kbc[sl*SSTR + 8*g + 4] = make_float4(x[4], x[5], x[6], x[7]);
        if (g < 2) {
            *(float4*)&kbc[sl*SSTR + 32 + 8*g    ] = make_float4(x[8],  x[9],  x[10], x[11]);
            *(float4*)&kbc[sl*SSTR + 32 + 8*g + 4] = make_float4(x[12], x[13], x[14], x[15]);
        }
        {
            int idx = tid, sm = idx / 12, off = idx - sm*12;
            float4 v = *(const float4*)&kbc[sm*SSTR + off*4];
            *(float4*)(stat + (size_t)(sbase + sm)*3072 + (size_t)ts*48 + off*4) = v;
        }
        if (tid < 64) {
            int idx = 128 + tid, sm = idx / 12, off = idx - sm*12;
            float4 v = *(const float4*)&kbc[sm*SSTR + off*4];
            *(float4*)(stat + (size_t)(sbase + sm)*3072 + (size_t)ts*48 + off*4) = v;
        }
    };
    auto write_outputs = [&](int ts) {
        half8 A0, A1;
        mkfrags(x, A0, A1);
        floatx4 acc = {boutp, boutp, boutp, boutp};
        acc = MFMA16(A0, wlds[12*64 + lane], acc);
        acc = MFMA16(A1, wlds[13*64 + lane], acc);
#pragma unroll
        for (int r = 0; r < 4; ++r)
            kbc[(4*g + r)*SSTR + sl] = sigmoid_fast(acc[r]);
        if (wid == 0) {
            int sm = lane >> 2, qq = lane & 3;
            float4 v = *(const float4*)&kbc[sm*SSTR + qq*4];
            *(float4*)(outp + (size_t)(sbase + sm)*1024 + (size_t)ts*16 + qq*4) = v;
        }
    };

    // ---------------- one dopri5 substep ----------------
    auto substep = [&](float hh) {
        float k1v[16], k3v[16], k4v[16], t[16];
        half8 A0, A1;
        // stage 1
        mkfrags(x, A0, A1);
        feval(A0, A1, kbc, hh);
        ldsk(kbc, k1v);
        // stage 2
#pragma unroll
        for (int j = 0; j < 16; ++j) t[j] = fmaf(0.2f, k1v[j], x[j]);
        mkfrags(t, A0, A1);
        feval(A0, A1, kb2, hh);          // k2 stays in LDS
        // stage 3
        {
            float k2t[16]; ldsk(kb2, k2t);
#pragma unroll
            for (int j = 0; j < 16; ++j)
                t[j] = x[j] + 0.075f*k1v[j] + 0.225f*k2t[j];
        }
        mkfrags(t, A0, A1);
        feval(A0, A1, kbc, hh);
        ldsk(kbc, k3v);
        // stage 4
        {
            float k2t[16]; ldsk(kb2, k2t);
#pragma unroll
            for (int j = 0; j < 16; ++j)
                t[j] = x[j] + (44.f/45.f)*k1v[j] + (-56.f/15.f)*k2t[j] + (32.f/9.f)*k3v[j];
        }
        mkfrags(t, A0, A1);
        feval(A0, A1, kbc, hh);
        ldsk(kbc, k4v);
        // stage 5
        {
            float k2t[16]; ldsk(kb2, k2t);
#pragma unroll
            for (int j = 0; j < 16; ++j)
                t[j] = x[j] + (19372.f/6561.f)*k1v[j] + (-25360.f/2187.f)*k2t[j]
                     + (64448.f/6561.f)*k3v[j] + (-212.f/729.f)*k4v[j];
        }
        mkfrags(t, A0, A1);
        feval(A0, A1, kb5, hh);          // k5 stays in LDS
        // stage 6
        {
            float k2t[16], k5t[16]; ldsk(kb2, k2t); ldsk(kb5, k5t);
#pragma unroll
            for (int j = 0; j < 16; ++j)
                t[j] = x[j] + (9017.f/3168.f)*k1v[j] + (-355.f/33.f)*k2t[j]
                     + (46732.f/5247.f)*k3v[j] + (49.f/176.f)*k4v[j]
                     + (-5103.f/18656.f)*k5t[j];
        }
        mkfrags(t, A0, A1);
        feval(A0, A1, kbc, hh);
        // final combination
        {
            float k6t[16], k5t[16]; ldsk(kbc, k6t); ldsk(kb5, k5t);
#pragma unroll
            for (int j = 0; j < 16; ++j)
                x[j] += (35.f/384.f)*k1v[j] + (500.f/1113.f)*k3v[j] + (125.f/192.f)*k4v[j]
                      + (-2187.f/6784.f)*k5t[j] + (11.f/84.f)*k6t[j];
        }
    };

    // ---------------- main loop ----------------
    __syncthreads();        // encoder reads done before staging overwrites kbc
    write_states(0);
    __syncthreads();        // staging reads done before sigmoid writes
    write_outputs(0);

#pragma unroll 1
    for (int iv = 0; iv < 63; ++iv) {
        const float hh = (pt[iv+1] - pt[iv]) * 0.125f;
#pragma unroll 1
        for (int sub = 0; sub < 8; ++sub) substep(hh);
        __syncthreads();    // k6 reads done before staging overwrites kbc
        write_states(iv + 1);
        __syncthreads();    // staging reads done before sigmoid writes
        write_outputs(iv + 1);
    }
}

extern "C" void kernel_launch(void* const* d_in, const int* in_sizes, int n_in,
                              void* d_out, int out_size, void* d_ws, size_t ws_size,
                              hipStream_t stream) {
    const float* meas = (const float*)d_in[0];
    const float* pt   = (const float*)d_in[1];
    const float* Wenc = (const float*)d_in[2];
    const float* benc = (const float*)d_in[3];
    const float* W1   = (const float*)d_in[4];
    const float* b1   = (const float*)d_in[5];
    const float* W2   = (const float*)d_in[6];
    const float* b2   = (const float*)d_in[7];
    const float* W3   = (const float*)d_in[8];
    const float* b3   = (const float*)d_in[9];
    const float* Wout = (const float*)d_in[10];
    const float* bout = (const float*)d_in[11];
    float* outp = (float*)d_out;                        // [B, T, 16]
    float* stat = outp + (size_t)16384 * 64 * 16;       // [B, T, 48]
    hipLaunchKernelGGL(node_fused, dim3(1024), dim3(128), 0, stream,
                       meas, pt, Wenc, benc, W1, b1, W2, b2, W3, b3, Wout, bout,
                       outp, stat);
}